// Round 7
// baseline (278.067 us; speedup 1.0000x reference)
//
#include <hip/hip_runtime.h>
#include <hip/hip_bf16.h>

// Problem constants (B,H,W,C) = (4,56,56,256), nh=8, K=7, lr=4, hd=32
#define BD 4
#define HD_ 56
#define WD 56
#define CD 256
#define NH 8
#define KW 7
#define LR 4
#define HDIM 32
#define MB (HD_*WD)              // 3136 rows per batch
#define NROWS (BD*MB)            // 12544 total rows
#define QK_PER_B (HD_*WD*32)     // 100352  (q/k per-batch elements)
#define V_PER_B  (HD_*WD*256)    // 802816

typedef short short8 __attribute__((ext_vector_type(8)));   // 8 bf16 (4 VGPRs)
typedef float floatx4 __attribute__((ext_vector_type(4)));  // MFMA C/D

static __device__ inline ushort f2bf(float f) {
    __hip_bfloat16 h = __float2bfloat16(f);
    return *(ushort*)&h;
}
static __device__ inline float bf2f(uint h16) {          // h16 = bf16 in low 16 bits
    union { uint u; float f; } c; c.u = h16 << 16; return c.f;
}
static __device__ inline float bf2f_hi(uint u) {         // bf16 in high 16 bits
    union { uint v; float f; } c; c.v = u & 0xffff0000u; return c.f;
}

// ---------------- fused prep: x->bf16 + transposed bf16 weights + bias -------
__global__ __launch_bounds__(256) void prep_all(
    const float* __restrict__ x,
    const float* __restrict__ Wq, const float* __restrict__ Wk,
    const float* __restrict__ Wv, const float* __restrict__ bq,
    const float* __restrict__ bk, const float* __restrict__ bv,
    const float* __restrict__ Wp,
    ushort* __restrict__ Xb, ushort* __restrict__ WpkT,
    ushort* __restrict__ WpT, float* __restrict__ pb)
{
    int blk = blockIdx.x;
    if (blk < 1568) {
        int i8 = (blk * 256 + threadIdx.x) * 8;
        float4 u = *(const float4*)&x[i8];
        float4 v = *(const float4*)&x[i8 + 4];
        union { ushort h[8]; uint4 q; } pk;
        pk.h[0] = f2bf(u.x); pk.h[1] = f2bf(u.y); pk.h[2] = f2bf(u.z); pk.h[3] = f2bf(u.w);
        pk.h[4] = f2bf(v.x); pk.h[5] = f2bf(v.y); pk.h[6] = f2bf(v.z); pk.h[7] = f2bf(v.w);
        *(uint4*)&Xb[i8] = pk.q;
    } else {
        int idx = (blk - 1568) * 256 + threadIdx.x;
        if (idx < 81920) {
            int n = idx >> 8, k = idx & 255;
            float v;
            if (n < 32)       v = Wq[k * 32 + n];
            else if (n < 64)  v = Wk[k * 32 + (n - 32)];
            else              v = Wv[k * 256 + (n - 64)];
            WpkT[idx] = f2bf(v);
        } else if (idx < 81920 + 65536) {
            int j = idx - 81920;
            int n = j >> 8, k = j & 255;
            WpT[j] = f2bf(Wp[k * 256 + n]);
        } else if (idx < 81920 + 65536 + 320) {
            int n = idx - (81920 + 65536);
            pb[n] = (n < 32) ? bq[n] : (n < 64) ? bk[n - 32] : bv[n - 64];
        }
    }
}

// ---------------- MFMA GEMM: QKV projection (ALL batches) ----------------
__global__ __launch_bounds__(256) void mfma_qkv(
    const ushort* __restrict__ Ag, const ushort* __restrict__ Bt,
    const float* __restrict__ pb, ushort* __restrict__ Qb,
    ushort* __restrict__ Kb, ushort* __restrict__ Vb)
{
    __shared__ ushort As[64 * 40];   // 64 rows x BK=32 (+8 pad) bf16
    __shared__ ushort Bs[64 * 40];

    const int t = threadIdx.x;
    const int m0 = blockIdx.y * 64;
    const int n0 = blockIdx.x * 64;
    const int r  = t >> 2;
    const int kq = (t & 3) << 3;
    const int lane = t & 63, w = t >> 6;
    const int col = lane & 15, quad = lane >> 4;
    const int q8 = quad << 3;

    floatx4 acc[4] = {{0,0,0,0},{0,0,0,0},{0,0,0,0},{0,0,0,0}};

    for (int k0 = 0; k0 < 256; k0 += 32) {
        uint4 av = *(const uint4*)&Ag[(m0 + r) * 256 + k0 + kq];
        uint4 bv = *(const uint4*)&Bt[(n0 + r) * 256 + k0 + kq];
        __syncthreads();
        *(uint4*)&As[r * 40 + kq] = av;
        *(uint4*)&Bs[r * 40 + kq] = bv;
        __syncthreads();
        short8 af = *(short8*)&As[((w << 4) + col) * 40 + q8];
#pragma unroll
        for (int nt = 0; nt < 4; ++nt) {
            short8 bf = *(short8*)&Bs[((nt << 4) + col) * 40 + q8];
            acc[nt] = __builtin_amdgcn_mfma_f32_16x16x32_bf16(af, bf, acc[nt], 0, 0, 0);
        }
    }

#pragma unroll
    for (int nt = 0; nt < 4; ++nt) {
        int gn = n0 + (nt << 4) + col;
        float bias = pb[gn];
#pragma unroll
        for (int rg = 0; rg < 4; ++rg) {
            int m = m0 + (w << 4) + (quad << 2) + rg;
            ushort h = f2bf(acc[nt][rg] + bias);
            if (n0 == 0 && nt < 2)      Qb[m * 32 + gn] = h;
            else if (n0 == 0)           Kb[m * 32 + (gn - 32)] = h;
            else                        Vb[m * 256 + (gn - 64)] = h;
        }
    }
}

// ---------------- MFMA GEMM: output projection (ALL batches) ----------------
__global__ __launch_bounds__(256) void mfma_out(
    const ushort* __restrict__ Ag, const ushort* __restrict__ Bt,
    const float* __restrict__ bp, float* __restrict__ out)
{
    __shared__ ushort As[64 * 40];
    __shared__ ushort Bs[64 * 40];

    const int t = threadIdx.x;
    const int m0 = blockIdx.y * 64;
    const int n0 = blockIdx.x * 64;
    const int r  = t >> 2;
    const int kq = (t & 3) << 3;
    const int lane = t & 63, w = t >> 6;
    const int col = lane & 15, quad = lane >> 4;
    const int q8 = quad << 3;

    floatx4 acc[4] = {{0,0,0,0},{0,0,0,0},{0,0,0,0},{0,0,0,0}};

    for (int k0 = 0; k0 < 256; k0 += 32) {
        uint4 av = *(const uint4*)&Ag[(m0 + r) * 256 + k0 + kq];
        uint4 bv = *(const uint4*)&Bt[(n0 + r) * 256 + k0 + kq];
        __syncthreads();
        *(uint4*)&As[r * 40 + kq] = av;
        *(uint4*)&Bs[r * 40 + kq] = bv;
        __syncthreads();
        short8 af = *(short8*)&As[((w << 4) + col) * 40 + q8];
#pragma unroll
        for (int nt = 0; nt < 4; ++nt) {
            short8 bf = *(short8*)&Bs[((nt << 4) + col) * 40 + q8];
            acc[nt] = __builtin_amdgcn_mfma_f32_16x16x32_bf16(af, bf, acc[nt], 0, 0, 0);
        }
    }

#pragma unroll
    for (int nt = 0; nt < 4; ++nt) {
        int gn = n0 + (nt << 4) + col;
        float bias = bp[gn];
#pragma unroll
        for (int rg = 0; rg < 4; ++rg) {
            int m = m0 + (w << 4) + (quad << 2) + rg;
            out[m * 256 + gn] = acc[nt][rg] + bias;
        }
    }
}

// ---------------- NATTEN attention: one LANE per query ----------------
// grid (7,7,32), block = 64 (one wave). Each lane: one query, all 32 channels.
// V in LDS with 80B/pos stride: bank-group (5*pos+c) mod 8 covers all 8
// four-bank groups per 8 consecutive queries -> conflict-free b128 agg reads.
__global__ __launch_bounds__(64) void natten_attn_t(
    const ushort* __restrict__ Qb, const ushort* __restrict__ Kb,
    const ushort* __restrict__ Vb, const float* __restrict__ rpb,
    ushort* __restrict__ Ab)
{
    __shared__ ushort Ks[196 * 4];    // 14x14 k-window, 8B/pos (1.5 KB)
    __shared__ ushort Vs[196 * 40];   // 14x14 v-window, 64B data + 16B pad (15.3 KB)
    __shared__ float  Rs[169];

    const int tj = blockIdx.x, ti = blockIdx.y;
    const int n = blockIdx.z & 7, b = blockIdx.z >> 3;
    const int t = threadIdx.x;        // 0..63
    const int i0 = ti * 8, j0 = tj * 8;
    const int rs = min(max(i0 - 3, 0), HD_ - 14);
    const int cs = min(max(j0 - 3, 0), WD - 14);

    // raw-reshape views:
    const ushort* kb = Kb + b * QK_PER_B + n * (HD_ * WD * LR);
    const ushort* vb = Vb + b * V_PER_B + n * (HD_ * WD * HDIM);

    for (int idx = t; idx < 196; idx += 64) {
        int r = idx / 14, c = idx % 14;
        *(uint2*)&Ks[idx * 4] = *(const uint2*)&kb[(rs + r) * (WD * LR) + (cs + c) * LR];
    }
    for (int idx = t; idx < 169; idx += 64) Rs[idx] = rpb[n * 169 + idx];
    for (int idx = t; idx < 784; idx += 64) {     // 196 pos x 4 quads
        int pos = idx >> 2, c = idx & 3;
        int r = pos / 14, cc = pos % 14;
        *(uint4*)&Vs[pos * 40 + c * 8] =
            *(const uint4*)&vb[(rs + r) * (WD * HDIM) + (cs + cc) * HDIM + c * 8];
    }
    __syncthreads();

    const int qi = t >> 3, qj = t & 7;
    const int i = i0 + qi, j = j0 + qj;
    const int sh = min(max(i - 3, 0), HD_ - KW);
    const int sw = min(max(j - 3, 0), WD - KW);
    const int oh = sh - rs, ow = sw - cs;

    union { uint2 u; uint w[2]; } qr;
    qr.u = *(const uint2*)&Qb[b * QK_PER_B + n * (HD_ * WD * LR) + i * (WD * LR) + j * LR];
    const float scale = 0.17677669529663687f;
    float qx = bf2f(qr.w[0] & 0xffff) * scale, qy = bf2f_hi(qr.w[0]) * scale;
    float qz = bf2f(qr.w[1] & 0xffff) * scale, qw = bf2f_hi(qr.w[1]) * scale;

    float s[49];
    float mx = -3.4e38f;
#pragma unroll
    for (int kh = 0; kh < KW; ++kh) {
        int rbase = (sh + kh - i + 6) * 13 + (sw - j + 6);
        int kpos  = (oh + kh) * 14 + ow;
#pragma unroll
        for (int kw = 0; kw < KW; ++kw) {
            union { uint2 u; uint w[2]; } kr;
            kr.u = *(const uint2*)&Ks[(kpos + kw) * 4];
            float d = Rs[rbase + kw];
            d = fmaf(qx, bf2f(kr.w[0] & 0xffff), d);
            d = fmaf(qy, bf2f_hi(kr.w[0]), d);
            d = fmaf(qz, bf2f(kr.w[1] & 0xffff), d);
            d = fmaf(qw, bf2f_hi(kr.w[1]), d);
            s[kh * KW + kw] = d;
            mx = fmaxf(mx, d);
        }
    }
    float sum = 0.f;
#pragma unroll
    for (int pp = 0; pp < 49; ++pp) { float e = __expf(s[pp] - mx); s[pp] = e; sum += e; }
    float inv = 1.0f / sum;

    float acc[32];
#pragma unroll
    for (int c = 0; c < 32; ++c) acc[c] = 0.f;

#pragma unroll
    for (int kh = 0; kh < KW; ++kh) {
        int kpos = (oh + kh) * 14 + ow;
#pragma unroll
        for (int kw = 0; kw < KW; ++kw) {
            float wt = s[kh * KW + kw] * inv;
            const ushort* vp = &Vs[(kpos + kw) * 40];
#pragma unroll
            for (int c4 = 0; c4 < 4; ++c4) {
                union { uint4 u; uint w[4]; } vr;
                vr.u = *(const uint4*)&vp[c4 * 8];
#pragma unroll
                for (int h = 0; h < 4; ++h) {
                    acc[c4 * 8 + 2 * h]     = fmaf(wt, bf2f(vr.w[h] & 0xffff), acc[c4 * 8 + 2 * h]);
                    acc[c4 * 8 + 2 * h + 1] = fmaf(wt, bf2f_hi(vr.w[h]),       acc[c4 * 8 + 2 * h + 1]);
                }
            }
        }
    }

    // bf16 store: 32 channels = 64B at channel block n*32
    ushort* op = &Ab[(((b * HD_ + i) * WD + j)) * CD + n * HDIM];
#pragma unroll
    for (int c4 = 0; c4 < 4; ++c4) {
        union { ushort h[8]; uint4 u; } pk;
#pragma unroll
        for (int h = 0; h < 8; ++h) pk.h[h] = f2bf(acc[c4 * 8 + h]);
        *(uint4*)&op[c4 * 8] = pk.u;
    }
}

extern "C" void kernel_launch(void* const* d_in, const int* in_sizes, int n_in,
                              void* d_out, int out_size, void* d_ws, size_t ws_size,
                              hipStream_t stream) {
    const float* x   = (const float*)d_in[0];
    const float* Wq  = (const float*)d_in[1];
    const float* bq  = (const float*)d_in[2];
    const float* Wk  = (const float*)d_in[3];
    const float* bk  = (const float*)d_in[4];
    const float* Wv  = (const float*)d_in[5];
    const float* bv  = (const float*)d_in[6];
    const float* rpb = (const float*)d_in[7];
    const float* Wp  = (const float*)d_in[8];
    const float* bp  = (const float*)d_in[9];
    float* out = (float*)d_out;

    // workspace layout — all-bf16 intermediates; ~21.2 MB of 256 MiB ws
    ushort* WpkT = (ushort*)d_ws;          // 81920
    ushort* WpT  = WpkT + 81920;           // 65536
    ushort* Xb   = WpT + 65536;            // 3211264
    ushort* Ab   = Xb + 3211264;           // 3211264
    ushort* Qb   = Ab + 3211264;           // 401408
    ushort* Kb   = Qb + BD * QK_PER_B;     // 401408
    ushort* Vb   = Kb + BD * QK_PER_B;     // 3211264
    float*  pb   = (float*)(Vb + BD * V_PER_B);  // 320

    prep_all<<<1568 + 578, 256, 0, stream>>>(
        x, Wq, Wk, Wv, bq, bk, bv, Wp, Xb, WpkT, WpT, pb);

    mfma_qkv<<<dim3(5, NROWS / 64), 256, 0, stream>>>(Xb, WpkT, pb, Qb, Kb, Vb);

    natten_attn_t<<<dim3(7, 7, 32), 64, 0, stream>>>(Qb, Kb, Vb, rpb, Ab);

    mfma_out<<<dim3(4, NROWS / 64), 256, 0, stream>>>(Ab, WpT, bp, out);
}

// Round 8
// 123.323 us; speedup vs baseline: 2.2548x; 2.2548x over previous
//
#include <hip/hip_runtime.h>
#include <hip/hip_bf16.h>

// Problem constants (B,H,W,C) = (4,56,56,256), nh=8, K=7, lr=4, hd=32
#define BD 4
#define HD_ 56
#define WD 56
#define CD 256
#define NH 8
#define KW 7
#define LR 4
#define HDIM 32
#define MB (HD_*WD)              // 3136 rows per batch
#define NROWS (BD*MB)            // 12544 total rows
#define QK_PER_B (HD_*WD*32)     // 100352  (q/k per-batch elements)
#define V_PER_B  (HD_*WD*256)    // 802816

typedef short short8 __attribute__((ext_vector_type(8)));   // 8 bf16 (4 VGPRs)
typedef float floatx4 __attribute__((ext_vector_type(4)));  // MFMA C/D

static __device__ inline ushort f2bf(float f) {
    __hip_bfloat16 h = __float2bfloat16(f);
    return *(ushort*)&h;
}
static __device__ inline float bf2f(uint h16) {          // h16 = bf16 in low 16 bits
    union { uint u; float f; } c; c.u = h16 << 16; return c.f;
}
static __device__ inline float bf2f_hi(uint u) {         // bf16 in high 16 bits
    union { uint v; float f; } c; c.v = u & 0xffff0000u; return c.f;
}

// ---------------- fused prep: x->bf16 + transposed bf16 weights + bias -------
__global__ __launch_bounds__(256) void prep_all(
    const float* __restrict__ x,
    const float* __restrict__ Wq, const float* __restrict__ Wk,
    const float* __restrict__ Wv, const float* __restrict__ bq,
    const float* __restrict__ bk, const float* __restrict__ bv,
    const float* __restrict__ Wp,
    ushort* __restrict__ Xb, ushort* __restrict__ WpkT,
    ushort* __restrict__ WpT, float* __restrict__ pb)
{
    int blk = blockIdx.x;
    if (blk < 1568) {
        int i8 = (blk * 256 + threadIdx.x) * 8;
        float4 u = *(const float4*)&x[i8];
        float4 v = *(const float4*)&x[i8 + 4];
        union { ushort h[8]; uint4 q; } pk;
        pk.h[0] = f2bf(u.x); pk.h[1] = f2bf(u.y); pk.h[2] = f2bf(u.z); pk.h[3] = f2bf(u.w);
        pk.h[4] = f2bf(v.x); pk.h[5] = f2bf(v.y); pk.h[6] = f2bf(v.z); pk.h[7] = f2bf(v.w);
        *(uint4*)&Xb[i8] = pk.q;
    } else {
        int idx = (blk - 1568) * 256 + threadIdx.x;
        if (idx < 81920) {
            int n = idx >> 8, k = idx & 255;
            float v;
            if (n < 32)       v = Wq[k * 32 + n];
            else if (n < 64)  v = Wk[k * 32 + (n - 32)];
            else              v = Wv[k * 256 + (n - 64)];
            WpkT[idx] = f2bf(v);
        } else if (idx < 81920 + 65536) {
            int j = idx - 81920;
            int n = j >> 8, k = j & 255;
            WpT[j] = f2bf(Wp[k * 256 + n]);
        } else if (idx < 81920 + 65536 + 320) {
            int n = idx - (81920 + 65536);
            pb[n] = (n < 32) ? bq[n] : (n < 64) ? bk[n - 32] : bv[n - 64];
        }
    }
}

// ---------------- MFMA GEMM: QKV projection (ALL batches) ----------------
__global__ __launch_bounds__(256) void mfma_qkv(
    const ushort* __restrict__ Ag, const ushort* __restrict__ Bt,
    const float* __restrict__ pb, ushort* __restrict__ Qb,
    ushort* __restrict__ Kb, ushort* __restrict__ Vb)
{
    __shared__ ushort As[64 * 40];   // 64 rows x BK=32 (+8 pad) bf16
    __shared__ ushort Bs[64 * 40];

    const int t = threadIdx.x;
    const int m0 = blockIdx.y * 64;
    const int n0 = blockIdx.x * 64;
    const int r  = t >> 2;
    const int kq = (t & 3) << 3;
    const int lane = t & 63, w = t >> 6;
    const int col = lane & 15, quad = lane >> 4;
    const int q8 = quad << 3;

    floatx4 acc[4] = {{0,0,0,0},{0,0,0,0},{0,0,0,0},{0,0,0,0}};

    for (int k0 = 0; k0 < 256; k0 += 32) {
        uint4 av = *(const uint4*)&Ag[(m0 + r) * 256 + k0 + kq];
        uint4 bv = *(const uint4*)&Bt[(n0 + r) * 256 + k0 + kq];
        __syncthreads();
        *(uint4*)&As[r * 40 + kq] = av;
        *(uint4*)&Bs[r * 40 + kq] = bv;
        __syncthreads();
        short8 af = *(short8*)&As[((w << 4) + col) * 40 + q8];
#pragma unroll
        for (int nt = 0; nt < 4; ++nt) {
            short8 bf = *(short8*)&Bs[((nt << 4) + col) * 40 + q8];
            acc[nt] = __builtin_amdgcn_mfma_f32_16x16x32_bf16(af, bf, acc[nt], 0, 0, 0);
        }
    }

#pragma unroll
    for (int nt = 0; nt < 4; ++nt) {
        int gn = n0 + (nt << 4) + col;
        float bias = pb[gn];
#pragma unroll
        for (int rg = 0; rg < 4; ++rg) {
            int m = m0 + (w << 4) + (quad << 2) + rg;
            ushort h = f2bf(acc[nt][rg] + bias);
            if (n0 == 0 && nt < 2)      Qb[m * 32 + gn] = h;
            else if (n0 == 0)           Kb[m * 32 + (gn - 32)] = h;
            else                        Vb[m * 256 + (gn - 64)] = h;
        }
    }
}

// ---------------- MFMA GEMM: output projection (ALL batches) ----------------
__global__ __launch_bounds__(256) void mfma_out(
    const ushort* __restrict__ Ag, const ushort* __restrict__ Bt,
    const float* __restrict__ bp, float* __restrict__ out)
{
    __shared__ ushort As[64 * 40];
    __shared__ ushort Bs[64 * 40];

    const int t = threadIdx.x;
    const int m0 = blockIdx.y * 64;
    const int n0 = blockIdx.x * 64;
    const int r  = t >> 2;
    const int kq = (t & 3) << 3;
    const int lane = t & 63, w = t >> 6;
    const int col = lane & 15, quad = lane >> 4;
    const int q8 = quad << 3;

    floatx4 acc[4] = {{0,0,0,0},{0,0,0,0},{0,0,0,0},{0,0,0,0}};

    for (int k0 = 0; k0 < 256; k0 += 32) {
        uint4 av = *(const uint4*)&Ag[(m0 + r) * 256 + k0 + kq];
        uint4 bv = *(const uint4*)&Bt[(n0 + r) * 256 + k0 + kq];
        __syncthreads();
        *(uint4*)&As[r * 40 + kq] = av;
        *(uint4*)&Bs[r * 40 + kq] = bv;
        __syncthreads();
        short8 af = *(short8*)&As[((w << 4) + col) * 40 + q8];
#pragma unroll
        for (int nt = 0; nt < 4; ++nt) {
            short8 bf = *(short8*)&Bs[((nt << 4) + col) * 40 + q8];
            acc[nt] = __builtin_amdgcn_mfma_f32_16x16x32_bf16(af, bf, acc[nt], 0, 0, 0);
        }
    }

#pragma unroll
    for (int nt = 0; nt < 4; ++nt) {
        int gn = n0 + (nt << 4) + col;
        float bias = bp[gn];
#pragma unroll
        for (int rg = 0; rg < 4; ++rg) {
            int m = m0 + (w << 4) + (quad << 2) + rg;
            out[m * 256 + gn] = acc[nt][rg] + bias;
        }
    }
}

// ---------------- NATTEN attention: two-pass fused softmax ----------------
// grid (7,7,32), block 256 = 4 lanes/query. Pass 1: score max (no s[] array).
// Pass 2: recompute score, exp, accumulate sum + V-aggregate in one loop.
// VGPR target <=64 via __launch_bounds__(256,8) -> 8 waves/SIMD latency hiding.
__global__ __launch_bounds__(256, 8) void natten_attn_t(
    const ushort* __restrict__ Qb, const ushort* __restrict__ Kb,
    const ushort* __restrict__ Vb, const float* __restrict__ rpb,
    ushort* __restrict__ Ab)
{
    __shared__ ushort Ks[196 * 4];       // 14x14 k-window, bf16 (1.5 KB)
    __shared__ ushort Vs[4 * 196 * 8];   // [oct][pos][8ch] bf16 (12.25 KB)
    __shared__ float  Rs[169];

    const int tj = blockIdx.x, ti = blockIdx.y;
    const int n = blockIdx.z & 7, b = blockIdx.z >> 3;
    const int t = threadIdx.x;
    const int i0 = ti * 8, j0 = tj * 8;
    const int rs = min(max(i0 - 3, 0), HD_ - 14);
    const int cs = min(max(j0 - 3, 0), WD - 14);

    // raw-reshape views:
    const ushort* kb = Kb + b * QK_PER_B + n * (HD_ * WD * LR);
    const ushort* vb = Vb + b * V_PER_B + n * (HD_ * WD * HDIM);

    if (t < 196) {
        int r = t / 14, c = t % 14;
        *(uint2*)&Ks[t * 4] = *(const uint2*)&kb[(rs + r) * (WD * LR) + (cs + c) * LR];
    }
    if (t < 169) Rs[t] = rpb[n * 169 + t];
    for (int idx = t; idx < 784; idx += 256) {      // 196 pos x 4 octs
        int oct = idx & 3, pos = idx >> 2;
        int r = pos / 14, c = pos % 14;
        *(uint4*)&Vs[(oct * 196 + pos) * 8] =
            *(const uint4*)&vb[(rs + r) * (WD * HDIM) + (cs + c) * HDIM + oct * 8];
    }
    __syncthreads();

    const int q  = t >> 2, p = t & 3;
    const int qi = q >> 3, qj = q & 7;
    const int i = i0 + qi, j = j0 + qj;
    const int sh = min(max(i - 3, 0), HD_ - KW);
    const int sw = min(max(j - 3, 0), WD - KW);
    const int oh = sh - rs, ow = sw - cs;

    union { uint2 u; uint w[2]; } qr;
    qr.u = *(const uint2*)&Qb[b * QK_PER_B + n * (HD_ * WD * LR) + i * (WD * LR) + j * LR];
    const float scale = 0.17677669529663687f;
    float qx = bf2f(qr.w[0] & 0xffff) * scale, qy = bf2f_hi(qr.w[0]) * scale;
    float qz = bf2f(qr.w[1] & 0xffff) * scale, qw = bf2f_hi(qr.w[1]) * scale;

    const int rb0 = (sh - i + 6) * 13 + (sw - j + 6);

    // ---- pass 1: running max only (no score array -> low VGPR) ----
    float mx = -3.4e38f;
    for (int kh = 0; kh < KW; ++kh) {
        int kpos  = (oh + kh) * 14 + ow;
        int rbase = rb0 + kh * 13;
#pragma unroll
        for (int kw = 0; kw < KW; ++kw) {
            union { uint2 u; uint w[2]; } kr;
            kr.u = *(const uint2*)&Ks[(kpos + kw) * 4];
            float d = Rs[rbase + kw];
            d = fmaf(qx, bf2f(kr.w[0] & 0xffff), d);
            d = fmaf(qy, bf2f_hi(kr.w[0]), d);
            d = fmaf(qz, bf2f(kr.w[1] & 0xffff), d);
            d = fmaf(qw, bf2f_hi(kr.w[1]), d);
            mx = fmaxf(mx, d);
        }
    }

    // ---- pass 2: recompute score, exp, fused sum + V aggregation ----
    float sum = 0.f;
    float a[8] = {0.f, 0.f, 0.f, 0.f, 0.f, 0.f, 0.f, 0.f};
    const ushort* vsl = &Vs[p * (196 * 8)];
    for (int kh = 0; kh < KW; ++kh) {
        int kpos  = (oh + kh) * 14 + ow;
        int rbase = rb0 + kh * 13;
#pragma unroll
        for (int kw = 0; kw < KW; ++kw) {
            union { uint2 u; uint w[2]; } kr;
            kr.u = *(const uint2*)&Ks[(kpos + kw) * 4];
            float d = Rs[rbase + kw];
            d = fmaf(qx, bf2f(kr.w[0] & 0xffff), d);
            d = fmaf(qy, bf2f_hi(kr.w[0]), d);
            d = fmaf(qz, bf2f(kr.w[1] & 0xffff), d);
            d = fmaf(qw, bf2f_hi(kr.w[1]), d);
            float e = __expf(d - mx);
            sum += e;
            union { uint4 u; uint w[4]; } vr;
            vr.u = *(const uint4*)&vsl[(kpos + kw) * 8];
#pragma unroll
            for (int c = 0; c < 4; ++c) {
                a[2 * c]     = fmaf(e, bf2f(vr.w[c] & 0xffff), a[2 * c]);
                a[2 * c + 1] = fmaf(e, bf2f_hi(vr.w[c]),       a[2 * c + 1]);
            }
        }
    }
    float inv = 1.0f / sum;

    // bf16 store: 8 channels = 16B at channel block n*32 + p*8
    union { ushort h[8]; uint4 u; } pk;
#pragma unroll
    for (int c = 0; c < 8; ++c) pk.h[c] = f2bf(a[c] * inv);
    *(uint4*)&Ab[(((b * HD_ + i) * WD + j)) * CD + n * HDIM + p * 8] = pk.u;
}

extern "C" void kernel_launch(void* const* d_in, const int* in_sizes, int n_in,
                              void* d_out, int out_size, void* d_ws, size_t ws_size,
                              hipStream_t stream) {
    const float* x   = (const float*)d_in[0];
    const float* Wq  = (const float*)d_in[1];
    const float* bq  = (const float*)d_in[2];
    const float* Wk  = (const float*)d_in[3];
    const float* bk  = (const float*)d_in[4];
    const float* Wv  = (const float*)d_in[5];
    const float* bv  = (const float*)d_in[6];
    const float* rpb = (const float*)d_in[7];
    const float* Wp  = (const float*)d_in[8];
    const float* bp  = (const float*)d_in[9];
    float* out = (float*)d_out;

    // workspace layout — all-bf16 intermediates; ~21.2 MB of 256 MiB ws
    ushort* WpkT = (ushort*)d_ws;          // 81920
    ushort* WpT  = WpkT + 81920;           // 65536
    ushort* Xb   = WpT + 65536;            // 3211264
    ushort* Ab   = Xb + 3211264;           // 3211264
    ushort* Qb   = Ab + 3211264;           // 401408
    ushort* Kb   = Qb + BD * QK_PER_B;     // 401408
    ushort* Vb   = Kb + BD * QK_PER_B;     // 3211264
    float*  pb   = (float*)(Vb + BD * V_PER_B);  // 320

    prep_all<<<1568 + 578, 256, 0, stream>>>(
        x, Wq, Wk, Wv, bq, bk, bv, Wp, Xb, WpkT, WpT, pb);

    mfma_qkv<<<dim3(5, NROWS / 64), 256, 0, stream>>>(Xb, WpkT, pb, Qb, Kb, Vb);

    natten_attn_t<<<dim3(7, 7, 32), 256, 0, stream>>>(Qb, Kb, Vb, rpb, Ab);

    mfma_out<<<dim3(4, NROWS / 64), 256, 0, stream>>>(Ab, WpT, bp, out);
}